// Round 14
// baseline (162.751 us; speedup 1.0000x reference)
//
#include <hip/hip_runtime.h>

// Trilinear feature-grid interpolation, v10.
// grid layout: [R][R][R][3] = [z][y][x][c], R=256, fp32 (192 MB).
//
// Round-13 evidence: v9's 83KB window -> 1 block/CU -> stage latency fully
// exposed (no TLP). v10: half-x blocks, 3-layer window of 9x1552B chunks =
// 41.9KB -> 3 blocks/CU at 512 thr; cross-block TLP fills stage bubbles.
// Bins: 16384 = (zl, yl>>3, xl>>7), CAP 256. Scatter uses a single 64KB
// LDS array (count, then overwrite with base) to keep 2 blocks/CU.

#define NB      16384
#define CAP     256u
#define SBLK    1024              // scatter block size
#define GBLK    512               // gather block size
#define CHF4    97                // float4 per x-chunk (129 cells + pad)
#define NCH     9                 // y-rows per layer
#define LAYERF4 (NCH * CHF4)      // 873 float4 per layer
#define LAYERF  (LAYERF4 * 4)     // 3492 floats
#define GRIDF4  12582912          // total float4 in grid

// ws layout: binned[16384*256] float4 = 64MB, then cur[16384]
#define CUR_OFF   67108864u
#define NEEDED    (67108864u + 65536u)

typedef float f4v __attribute__((ext_vector_type(4)));
typedef float f2v __attribute__((ext_vector_type(2)));
typedef f4v f4u __attribute__((aligned(8)));
typedef f2v f2u __attribute__((aligned(8)));

__device__ __forceinline__ void cell_of(float p, int& l, float& t) {
    float s = p * 255.0f;
    int v = (int)floorf(s);
    v = v < 0 ? 0 : (v > 254 ? 254 : v);
    l = v;
    t = s - (float)v;
}

// bin: K = [zl:8][yb:5][xh:1]  (half-x, 8 y-cells, 1 z-cell)
__device__ __forceinline__ int fine_bin3(float px, float py, float pz) {
    int xl, yl, zl; float tx, ty, tz;
    cell_of(px, xl, tx);
    cell_of(py, yl, ty);
    cell_of(pz, zl, tz);
    return (zl << 6) | (((yl >> 3) << 1)) | (xl >> 7);
}

__device__ __forceinline__ void direct_lerp(const float* __restrict__ grid,
                                            float* __restrict__ out, int i,
                                            int xl, int yl, int zl,
                                            float tx, float ty, float tz) {
    int b00 = (zl * 65536 + yl * 256 + xl) * 3;
    int b01 = b00 + 768, b10 = b00 + 196608, b11 = b10 + 768;
    float s00[6], s01[6], s10[6], s11[6];
#pragma unroll
    for (int k = 0; k < 6; ++k) s00[k] = grid[b00 + k];
#pragma unroll
    for (int k = 0; k < 6; ++k) s01[k] = grid[b01 + k];
#pragma unroll
    for (int k = 0; k < 6; ++k) s10[k] = grid[b10 + k];
#pragma unroll
    for (int k = 0; k < 6; ++k) s11[k] = grid[b11 + k];
#pragma unroll
    for (int c = 0; c < 3; ++c) {
        float c00 = s00[c] * (1.0f - tx) + s00[c + 3] * tx;
        float c01 = s01[c] * (1.0f - tx) + s01[c + 3] * tx;
        float c10 = s10[c] * (1.0f - tx) + s10[c + 3] * tx;
        float c11 = s11[c] * (1.0f - tx) + s11[c + 3] * tx;
        float c0 = c00 * (1.0f - ty) + c01 * ty;
        float c1 = c10 * (1.0f - ty) + c11 * ty;
        out[3 * i + c] = c0 * (1.0f - tz) + c1 * tz;
    }
}

// ---------------- pass 0: init cursors ----------------
__global__ __launch_bounds__(1024) void k_init(unsigned* __restrict__ cur) {
    int i = blockIdx.x * 1024 + threadIdx.x;
    if (i < NB) cur[i] = (unsigned)i * CAP;
}

// ---------------- pass 1: block-aggregated scatter (2 pts/thread) ----------------
// Single LDS array: holds per-bin COUNT during phase 1, then is overwritten
// with the bin's global BASE slot (64 KB -> 2 blocks/CU).
__global__ __launch_bounds__(SBLK) void k_scatter(const float* __restrict__ inp,
                                                  const float* __restrict__ grid,
                                                  float4* __restrict__ binned,
                                                  unsigned* __restrict__ cur,
                                                  float* __restrict__ out, int n) {
    __shared__ unsigned agg[NB];
    int t = threadIdx.x;
    int P = n >> 1;
    int stride = gridDim.x * SBLK;
    int iters = (P + stride - 1) / stride;

    if ((n & 1) && blockIdx.x == 0 && t == 0) {
        int i = n - 1;
        float px = inp[3 * i], py = inp[3 * i + 1], pz = inp[3 * i + 2];
        int b = fine_bin3(px, py, pz);
        unsigned r = atomicAdd(&cur[b], 1u);
        if (r - (unsigned)b * CAP < CAP) {
            float4 v; v.x = px; v.y = py; v.z = pz; v.w = __uint_as_float((unsigned)i);
            binned[r] = v;
        } else {
            int xl, yl, zl; float tx, ty, tz;
            cell_of(px, xl, tx); cell_of(py, yl, ty); cell_of(pz, zl, tz);
            direct_lerp(grid, out, i, xl, yl, zl, tx, ty, tz);
        }
    }

    for (int it = 0; it < iters; ++it) {
        int pr = it * stride + blockIdx.x * SBLK + t;
        for (int k = t; k < NB; k += SBLK) agg[k] = 0;
        __syncthreads();
        int b0 = 0, b1 = 0; unsigned r0 = 0, r1 = 0;
        float4 p0, p1;
        bool valid = (pr < P);
        if (valid) {
            f4v a = *(const f4u*)(inp + 6 * pr);
            f2v b = *(const f2u*)(inp + 6 * pr + 4);
            p0.x = a.x; p0.y = a.y; p0.z = a.z;
            p0.w = __uint_as_float((unsigned)(2 * pr));
            p1.x = a.w; p1.y = b.x; p1.z = b.y;
            p1.w = __uint_as_float((unsigned)(2 * pr + 1));
            b0 = fine_bin3(p0.x, p0.y, p0.z);
            b1 = fine_bin3(p1.x, p1.y, p1.z);
            r0 = atomicAdd(&agg[b0], 1u);
            r1 = atomicAdd(&agg[b1], 1u);
        }
        __syncthreads();
        for (int k = t; k < NB; k += SBLK) {
            unsigned c = agg[k];
            if (c) agg[k] = atomicAdd(&cur[k], c);   // count -> base
        }
        __syncthreads();
        if (valid) {
            unsigned s0 = agg[b0] + r0;
            unsigned s1 = agg[b1] + r1;
            if (s0 - (unsigned)b0 * CAP < CAP) binned[s0] = p0;
            else {
                int xl, yl, zl; float tx, ty, tz;
                cell_of(p0.x, xl, tx); cell_of(p0.y, yl, ty); cell_of(p0.z, zl, tz);
                direct_lerp(grid, out, 2 * pr, xl, yl, zl, tx, ty, tz);
            }
            if (s1 - (unsigned)b1 * CAP < CAP) binned[s1] = p1;
            else {
                int xl, yl, zl; float tx, ty, tz;
                cell_of(p1.x, xl, tx); cell_of(p1.y, yl, ty); cell_of(p1.z, zl, tz);
                direct_lerp(grid, out, 2 * pr + 1, xl, yl, zl, tx, ty, tz);
            }
        }
        __syncthreads();
    }
}

// ---------------- pass 2: z-walk gather, rolling 3-layer window ----------------
// Stage layer zg_: 9 y-row chunks of 97 float4 ([zg][y0+c][x0..x0+129) cells),
// each chunk a contiguous 1552B burst; LDS dest linear (u*16).
#define STAGE_LAYER(zg_, slot_)                                                 \
    do {                                                                        \
        size_t basef4 = (size_t)(zg_)*49152 + (size_t)y0 * 192 + (size_t)xq;    \
        float* dst = &slab[(slot_) * LAYERF];                                   \
        for (int u = t; u < LAYERF4; u += GBLK) {                               \
            int chunk = u / CHF4;                                               \
            int j = u - chunk * CHF4;                                           \
            size_t sf4 = basef4 + (size_t)chunk * 192 + (size_t)j;              \
            if (sf4 > (size_t)(GRIDF4 - 1)) sf4 = (size_t)(GRIDF4 - 1);         \
            __builtin_amdgcn_global_load_lds(                                   \
                (const __attribute__((address_space(1))) unsigned int*)(grid + sf4 * 4), \
                (__attribute__((address_space(3))) unsigned int*)&dst[(size_t)u * 4], \
                16, 0, 0);                                                      \
        }                                                                       \
    } while (0)

__global__ __launch_bounds__(GBLK) void k_gather(const float4* __restrict__ binned,
                                                 const float* __restrict__ grid,
                                                 const unsigned* __restrict__ cur,
                                                 float* __restrict__ out) {
    __shared__ __align__(16) float slab[3 * LAYERF];   // 41904 B -> 3 blocks/CU
    int t = threadIdx.x;
    // 1024 blocks; XCD-chunked: XCD k owns sb in [128k,128k+128) = 2
    // contiguous z-segments x all y x both halves (L2 halo reuse).
    int sb = ((blockIdx.x & 7) << 7) | (blockIdx.x >> 3);   // bijective [0,1024)
    int zb = sb >> 6;             // 16 z-segments of 16 cells
    int yb = (sb >> 1) & 31;      // 32 y-bins of 8 cells
    int xh = sb & 1;              // x half
    int z0 = zb << 4;
    int y0 = yb << 3;
    int x0 = xh << 7;
    int xq = xh * 96;             // x0 in float4 units (x0*3/4)

    int zg1 = z0 + 1 > 255 ? 255 : z0 + 1;
    STAGE_LAYER(z0,  0);
    STAGE_LAYER(zg1, 1);

    for (int zc = 0; zc < 16; ++zc) {
        int sA = (zc % 3) * LAYERF;
        int sB = ((zc + 1) % 3) * LAYERF;
        // __syncthreads emits s_waitcnt vmcnt(0) lgkmcnt(0) + s_barrier:
        // drains the stage of layer zc+1; fences slot (zc+2)%3's readers.
        __syncthreads();
        if (zc < 15) {
            int zg = z0 + zc + 2; zg = zg > 255 ? 255 : zg;
            STAGE_LAYER(zg, (zc + 2) % 3);
        }

        int K = ((z0 + zc) << 6) | (yb << 1) | xh;
        unsigned start = (unsigned)K * CAP;
        unsigned count = cur[K] - start;
        if (count > CAP) count = CAP;

        for (unsigned p = (unsigned)t; p < count; p += (unsigned)GBLK) {
            float4 v = binned[start + p];
            unsigned idx = __float_as_uint(v.w);

            int xl, yl, zl; float tx, ty, tz;
            cell_of(v.x, xl, tx);
            cell_of(v.y, yl, ty);
            cell_of(v.z, zl, tz);
            int row = yl - y0;                 // 0..7
            int xc  = xl - x0;                 // 0..127

            int o00 = sA + row * 388 + xc * 3;
            int o01 = o00 + 388;
            int o10 = sB + row * 388 + xc * 3;
            int o11 = o10 + 388;

#define SEG_READ(b, s)                                   \
            do {                                         \
                int e_ = (b) & ~1;                       \
                bool d_ = ((b) & 1) != 0;                \
                f2v q0 = *(const f2u*)(&slab[e_]);       \
                f2v q1 = *(const f2u*)(&slab[e_ + 2]);   \
                f2v q2 = *(const f2u*)(&slab[e_ + 4]);   \
                f2v q3 = *(const f2u*)(&slab[e_ + 6]);   \
                s[0] = d_ ? q0.y : q0.x;                 \
                s[1] = d_ ? q1.x : q0.y;                 \
                s[2] = d_ ? q1.y : q1.x;                 \
                s[3] = d_ ? q2.x : q1.y;                 \
                s[4] = d_ ? q2.y : q2.x;                 \
                s[5] = d_ ? q3.x : q2.y;                 \
            } while (0)

            float s00[6], s01[6], s10[6], s11[6];
            SEG_READ(o00, s00);   // (zl,   yl)
            SEG_READ(o01, s01);   // (zl,   yl+1)
            SEG_READ(o10, s10);   // (zl+1, yl)
            SEG_READ(o11, s11);   // (zl+1, yl+1)
#undef SEG_READ

            float o[3];
#pragma unroll
            for (int c = 0; c < 3; ++c) {
                float c00 = s00[c] * (1.0f - tx) + s00[c + 3] * tx;
                float c01 = s01[c] * (1.0f - tx) + s01[c + 3] * tx;
                float c10 = s10[c] * (1.0f - tx) + s10[c + 3] * tx;
                float c11 = s11[c] * (1.0f - tx) + s11[c + 3] * tx;
                float c0 = c00 * (1.0f - ty) + c01 * ty;
                float c1 = c10 * (1.0f - ty) + c11 * ty;
                o[c] = c0 * (1.0f - tz) + c1 * tz;
            }
            float3 w; w.x = o[0]; w.y = o[1]; w.z = o[2];
            *(float3*)(out + 3 * (size_t)idx) = w;
        }
    }
}

// ---------------- fallback: direct ----------------
__global__ __launch_bounds__(256) void k_direct(const float* __restrict__ inp,
                                                const float* __restrict__ grid,
                                                float* __restrict__ out, int n) {
    int i = blockIdx.x * blockDim.x + threadIdx.x;
    if (i >= n) return;
    int xl, yl, zl; float tx, ty, tz;
    cell_of(inp[3 * i + 0], xl, tx);
    cell_of(inp[3 * i + 1], yl, ty);
    cell_of(inp[3 * i + 2], zl, tz);
    direct_lerp(grid, out, i, xl, yl, zl, tx, ty, tz);
}

extern "C" void kernel_launch(void* const* d_in, const int* in_sizes, int n_in,
                              void* d_out, int out_size, void* d_ws, size_t ws_size,
                              hipStream_t stream) {
    const float* inp  = (const float*)d_in[0];  // [N][3]
    const float* grid = (const float*)d_in[1];  // [256][256][256][3]
    float* out = (float*)d_out;                 // [N][3]
    int n = in_sizes[0] / 3;

    if (ws_size < (size_t)NEEDED) {
        int blocks = (n + 255) / 256;
        k_direct<<<blocks, 256, 0, stream>>>(inp, grid, out, n);
        return;
    }

    char* ws = (char*)d_ws;
    float4*   binned = (float4*)ws;
    unsigned* cur    = (unsigned*)(ws + CUR_OFF);

    k_init   <<<16,   1024, 0, stream>>>(cur);
    k_scatter<<<512,  SBLK, 0, stream>>>(inp, grid, binned, cur, out, n);
    k_gather <<<1024, GBLK, 0, stream>>>(binned, grid, cur, out);
}